// Round 9
// baseline (171.724 us; speedup 1.0000x reference)
//
#include <hip/hip_runtime.h>

typedef __bf16 bf16;
typedef __attribute__((ext_vector_type(8))) __bf16 bf16x8;
typedef __attribute__((ext_vector_type(4))) __bf16 bf16x4;
typedef __attribute__((ext_vector_type(4))) float f32x4;

constexpr int Bb = 8;
constexpr int Ss = 1024;
constexpr int Ee = 128;
constexpr int Hh = 8;
constexpr int Dd = 128;
constexpr int HD = 1024;

// async 16B global -> LDS (wave-uniform LDS base + lane*16, per-lane global src)
__device__ __forceinline__ void gl_lds16(const bf16* gp, bf16* lp) {
    __builtin_amdgcn_global_load_lds(
        (const __attribute__((address_space(1))) unsigned int*)gp,
        (__attribute__((address_space(3))) unsigned int*)lp, 16, 0, 0);
}

// ---------------------------------------------------------------------------
// K1: QKV projection, fully fused (no pre-convert pass).  Reads fp32 x and
// fp32 W directly, cvt to bf16 during LDS staging.  Wq gets log2e/sqrt(128)
// folded at staging so attention scores come out in log2 units.
// grid (64 rb, 8 h, 3 which), block 256.  Q/K -> [b,h,s,d]; V -> [b,h,d,s]
// (operand swap).  Padded 136-stride LDS: 2-way banks (free).
// ---------------------------------------------------------------------------
__global__ __launch_bounds__(256, 2) void k_qkv(
    const float* __restrict__ qin, const float* __restrict__ kin, const float* __restrict__ vin,
    const float* __restrict__ Wq, const float* __restrict__ Wk, const float* __restrict__ Wv,
    bf16* __restrict__ Qh, bf16* __restrict__ Kh, bf16* __restrict__ Vt)
{
    const int rb    = blockIdx.x;
    const int h     = blockIdx.y;
    const int which = blockIdx.z;
    const float* x = (which == 0) ? qin : (which == 1) ? kin : vin;
    const float* W = (which == 0) ? Wq  : (which == 1) ? Wk  : Wv;
    const float ws = (which == 0) ? 0.12751741530603157f : 1.0f;  // log2e/sqrt(128)

    __shared__ bf16 Xs[128][136];
    __shared__ bf16 Ws[128][136];

    const int tid  = threadIdx.x;
    const int wv   = tid >> 6;
    const int lane = tid & 63;
    const int lo   = lane & 15;
    const int q4   = lane >> 4;

#pragma unroll
    for (int t = 0; t < 8; ++t) {
        int c = tid + t * 256;               // 2048 chunks of 8 elems
        int row = c >> 4, c8 = (c & 15) << 3;
        const float* xp = &x[(rb * 128 + row) * Ee + c8];
        float4 f0 = *(const float4*)xp;
        float4 f1 = *(const float4*)(xp + 4);
        bf16x8 p;
        p[0] = (bf16)f0.x; p[1] = (bf16)f0.y; p[2] = (bf16)f0.z; p[3] = (bf16)f0.w;
        p[4] = (bf16)f1.x; p[5] = (bf16)f1.y; p[6] = (bf16)f1.z; p[7] = (bf16)f1.w;
        *(bf16x8*)&Xs[row][c8] = p;
        const float* wp = &W[(h * 128 + row) * Ee + c8];
        float4 g0 = *(const float4*)wp;
        float4 g1 = *(const float4*)(wp + 4);
        bf16x8 w;
        w[0] = (bf16)(g0.x * ws); w[1] = (bf16)(g0.y * ws);
        w[2] = (bf16)(g0.z * ws); w[3] = (bf16)(g0.w * ws);
        w[4] = (bf16)(g1.x * ws); w[5] = (bf16)(g1.y * ws);
        w[6] = (bf16)(g1.z * ws); w[7] = (bf16)(g1.w * ws);
        *(bf16x8*)&Ws[row][c8] = w;
    }
    __syncthreads();

    const bf16 (*Ap)[136] = (which == 2) ? Ws : Xs;
    const bf16 (*Bp)[136] = (which == 2) ? Xs : Ws;

    f32x4 acc[2][8];
#pragma unroll
    for (int i = 0; i < 2; ++i)
#pragma unroll
        for (int j = 0; j < 8; ++j) acc[i][j] = f32x4{0.f, 0.f, 0.f, 0.f};

#pragma unroll
    for (int kq = 0; kq < 4; ++kq) {
        bf16x8 a[2], b8[8];
#pragma unroll
        for (int ri = 0; ri < 2; ++ri)
            a[ri] = *(const bf16x8*)&Ap[wv * 32 + ri * 16 + lo][kq * 32 + q4 * 8];
#pragma unroll
        for (int cj = 0; cj < 8; ++cj)
            b8[cj] = *(const bf16x8*)&Bp[cj * 16 + lo][kq * 32 + q4 * 8];
#pragma unroll
        for (int ri = 0; ri < 2; ++ri)
#pragma unroll
            for (int cj = 0; cj < 8; ++cj)
                acc[ri][cj] = __builtin_amdgcn_mfma_f32_16x16x32_bf16(
                    a[ri], b8[cj], acc[ri][cj], 0, 0, 0);
    }

    const int bb = rb >> 3;
    const int s0 = (rb & 7) * 128;
    if (which < 2) {
        bf16* dst = ((which == 0) ? Qh : Kh) + (bb * Hh + h) * Ss * Dd;
#pragma unroll
        for (int ri = 0; ri < 2; ++ri)
#pragma unroll
            for (int cj = 0; cj < 8; ++cj)
#pragma unroll
                for (int r = 0; r < 4; ++r) {
                    int row = wv * 32 + ri * 16 + q4 * 4 + r;
                    int col = cj * 16 + lo;
                    dst[(s0 + row) * Dd + col] = (bf16)acc[ri][cj][r];
                }
    } else {
        bf16* dst = Vt + (bb * Hh + h) * Dd * Ss;
#pragma unroll
        for (int ri = 0; ri < 2; ++ri)
#pragma unroll
            for (int cj = 0; cj < 8; ++cj)
#pragma unroll
                for (int r = 0; r < 4; ++r) {
                    int row = wv * 32 + ri * 16 + q4 * 4 + r;   // d
                    int col = cj * 16 + lo;                     // s-local
                    dst[row * Ss + s0 + col] = (bf16)acc[ri][cj][r];
                }
    }
}

// ---------------------------------------------------------------------------
// K2: streaming attention (verbatim R8 — verified).  P-in-register, two
// 64-key tiles per barrier window, anti-phase wave groups (waves wv and wv+4
// share a SIMD and process the window's tiles in opposite order -> each SIMD
// always has one MFMA-phase and one VALU/LDS-phase wave).  Raw v_exp_f32.
// block 512 = 8 waves (32 qrows each); grid (64 bh, 4 qg); 1 block/CU.
// ---------------------------------------------------------------------------
__global__ __launch_bounds__(512, 2) void k_attn(
    const bf16* __restrict__ Qh, const bf16* __restrict__ Kh, const bf16* __restrict__ Vt,
    const float* __restrict__ mask, bf16* __restrict__ oc)
{
    const int bh = blockIdx.x;
    const int qg = blockIdx.y;     // 0..3, 256 qrows each
    const int b  = bh >> 3;
    const int h  = bh & 7;
    const int tid  = threadIdx.x;
    const int wv   = tid >> 6;     // 0..7
    const int lane = tid & 63;
    const int lo   = lane & 15;
    const int q4   = lane >> 4;

    __shared__ bf16 KsL[4][64 * 128];   // 4 x 16 KB  [key' perm][d-chunk swz]
    __shared__ bf16 VsL[4][128 * 64];   // 4 x 16 KB  [d][key-chunk swz]
    __shared__ float maskS[1024];       // 4 KB, pre-scaled by log2(e)

    const bf16* Qb = Qh + bh * Ss * Dd;
    const bf16* Kb = Kh + bh * Ss * Dd;
    const bf16* Vb = Vt + bh * Dd * Ss;

    auto stage = [&](int bi, int j0) {
#pragma unroll
        for (int t = 0; t < 2; ++t) {
            int i = wv * 2 + t;                    // 0..15
            int row = i * 4 + (lane >> 4);         // LDS row r' (key')
            int grow = (row & 32) + (((row >> 2) & 3) << 3)
                     + (((row >> 4) & 1) << 2) + (row & 3);
            int g = (lane & 15) ^ (row & 7);
            gl_lds16(Kb + (j0 + grow) * Dd + g * 8, &KsL[bi][i * 512]);
        }
#pragma unroll
        for (int t = 0; t < 2; ++t) {
            int i = wv * 2 + t;
            int row = i * 8 + (lane >> 3);         // d
            int g = (lane & 7) ^ (row & 7);
            gl_lds16(Vb + row * Ss + j0 + g * 8, &VsL[bi][i * 512]);
        }
    };

    stage(0, 0);
    stage(1, 64);   // window 0 in flight

#pragma unroll
    for (int t = 0; t < 2; ++t)
        maskS[tid + t * 512] = mask[b * Ss + tid + t * 512] * 1.4426950408889634f;

    // persistent Q fragments (pre-scaled): B-operand of QK.
    const int q0 = qg * 256 + wv * 32;
    bf16x8 qf[2][4];
#pragma unroll
    for (int nt = 0; nt < 2; ++nt)
#pragma unroll
        for (int kq = 0; kq < 4; ++kq)
            qf[nt][kq] = *(const bf16x8*)&Qb[(q0 + nt * 16 + lo) * Dd + kq * 32 + q4 * 8];

    f32x4 accO[8][2];                // O^T[d-tile dm][qrow-tile nt]
#pragma unroll
    for (int dm = 0; dm < 8; ++dm)
#pragma unroll
        for (int nt = 0; nt < 2; ++nt) accO[dm][nt] = f32x4{0.f, 0.f, 0.f, 0.f};
    float lsum[2] = {0.f, 0.f};

    const int sw = lo & 7;   // read-side chunk swizzle key

    auto compute = [&](int bi, int j0) {
        // QK: S^T[key'][qrow], 4 key'-tiles x 2 qrow-tiles
        f32x4 sc[4][2];
#pragma unroll
        for (int c = 0; c < 4; ++c)
#pragma unroll
            for (int nt = 0; nt < 2; ++nt) sc[c][nt] = f32x4{0.f, 0.f, 0.f, 0.f};
#pragma unroll
        for (int kq = 0; kq < 4; ++kq) {
            bf16x8 kf[4];
#pragma unroll
            for (int c = 0; c < 4; ++c)
                kf[c] = *(const bf16x8*)&KsL[bi][(c * 16 + lo) * 128 + (((kq << 2) + q4) ^ sw) * 8];
#pragma unroll
            for (int c = 0; c < 4; ++c)
#pragma unroll
                for (int nt = 0; nt < 2; ++nt)
                    sc[c][nt] = __builtin_amdgcn_mfma_f32_16x16x32_bf16(
                        kf[c], qf[nt][kq], sc[c][nt], 0, 0, 0);
        }

        // exp2 (raw v_exp_f32) + pack into PV B-fragments.
        bf16x8 p8[2][2];   // [kb][nt]
#pragma unroll
        for (int kb = 0; kb < 2; ++kb) {
#pragma unroll
            for (int t = 0; t < 2; ++t) {
                const float4 mv = *(const float4*)&maskS[j0 + kb * 32 + q4 * 8 + t * 4];
                const int c = kb * 2 + t;
#pragma unroll
                for (int nt = 0; nt < 2; ++nt) {
                    float e0 = __builtin_amdgcn_exp2f(sc[c][nt][0] + mv.x);
                    float e1 = __builtin_amdgcn_exp2f(sc[c][nt][1] + mv.y);
                    float e2 = __builtin_amdgcn_exp2f(sc[c][nt][2] + mv.z);
                    float e3 = __builtin_amdgcn_exp2f(sc[c][nt][3] + mv.w);
                    lsum[nt] += (e0 + e1) + (e2 + e3);
                    p8[kb][nt][t * 4 + 0] = (bf16)e0;
                    p8[kb][nt][t * 4 + 1] = (bf16)e1;
                    p8[kb][nt][t * 4 + 2] = (bf16)e2;
                    p8[kb][nt][t * 4 + 3] = (bf16)e3;
                }
            }
        }

        // PV: O^T[d][qrow] += V^T-frag · P-frag
#pragma unroll
        for (int kb = 0; kb < 2; ++kb)
#pragma unroll
            for (int dm = 0; dm < 8; ++dm) {
                bf16x8 vf = *(const bf16x8*)&VsL[bi][(dm * 16 + lo) * 64 + (((kb << 2) + q4) ^ sw) * 8];
#pragma unroll
                for (int nt = 0; nt < 2; ++nt)
                    accO[dm][nt] = __builtin_amdgcn_mfma_f32_16x16x32_bf16(
                        vf, p8[kb][nt], accO[dm][nt], 0, 0, 0);
            }
    };

    const bool grpB = (wv >= 4);   // waves wv and wv+4 share a SIMD -> anti-phase

    for (int w = 0; w < 8; ++w) {
        const int t0 = 2 * w;
        __syncthreads();                       // window w's 2 buffers ready
        if (w < 7) {                           // prefetch window w+1
            stage((t0 + 2) & 3, (t0 + 2) * 64);
            stage((t0 + 3) & 3, (t0 + 3) * 64);
        }
        if (grpB) {
            compute((t0 + 1) & 3, (t0 + 1) * 64);   // B then A
            compute(t0 & 3, t0 * 64);
        } else {
            compute(t0 & 3, t0 * 64);               // A then B
            compute((t0 + 1) & 3, (t0 + 1) * 64);
        }
    }

    // epilogue: row sums (reduce over q4 quads), normalize, store O.
#pragma unroll
    for (int nt = 0; nt < 2; ++nt) {
        float s = lsum[nt];
        s += __shfl_xor(s, 16, 64);
        s += __shfl_xor(s, 32, 64);
        float inv = 1.0f / (s + 1e-12f);
        int sg = q0 + nt * 16 + lo;
        bf16* dst = oc + (b * Ss + sg) * HD + h * 128;
#pragma unroll
        for (int dm = 0; dm < 8; ++dm) {
            bf16x4 o;
#pragma unroll
            for (int r = 0; r < 4; ++r) o[r] = (bf16)(accO[dm][nt][r] * inv);
            *(bf16x4*)&dst[dm * 16 + q4 * 4] = o;
        }
    }
}

// ---------------------------------------------------------------------------
// K3: output projection + bias, streaming (unchanged).
// ---------------------------------------------------------------------------
__global__ __launch_bounds__(256, 4) void k_proj(
    const bf16* __restrict__ oc, const float* __restrict__ Wc,
    const float* __restrict__ bc, float* __restrict__ out)
{
    const int mt   = blockIdx.x;
    const int tid  = threadIdx.x;
    const int wv   = tid >> 6;
    const int lane = tid & 63;
    const int lo   = lane & 15;
    const int q4   = lane >> 4;

    f32x4 acc[2];
    acc[0] = f32x4{0.f, 0.f, 0.f, 0.f};
    acc[1] = f32x4{0.f, 0.f, 0.f, 0.f};

    const bf16* arow = oc + (mt * 16 + lo) * HD + q4 * 8;

    for (int kc = 0; kc < 8; ++kc) {
        const int k0 = kc * 128;
        bf16x8 a[4];
#pragma unroll
        for (int kq = 0; kq < 4; ++kq)
            a[kq] = *(const bf16x8*)&arow[k0 + kq * 32];
#pragma unroll
        for (int cj = 0; cj < 2; ++cj) {
            const int n = wv * 32 + cj * 16 + lo;
#pragma unroll
            for (int kq = 0; kq < 4; ++kq) {
                const float* wp = &Wc[n * HD + k0 + kq * 32 + q4 * 8];
                float4 f0 = *(const float4*)wp;
                float4 f1 = *(const float4*)(wp + 4);
                bf16x8 bfr;
                bfr[0] = (bf16)f0.x; bfr[1] = (bf16)f0.y; bfr[2] = (bf16)f0.z; bfr[3] = (bf16)f0.w;
                bfr[4] = (bf16)f1.x; bfr[5] = (bf16)f1.y; bfr[6] = (bf16)f1.z; bfr[7] = (bf16)f1.w;
                acc[cj] = __builtin_amdgcn_mfma_f32_16x16x32_bf16(
                    a[kq], bfr, acc[cj], 0, 0, 0);
            }
        }
    }

#pragma unroll
    for (int cj = 0; cj < 2; ++cj) {
        int col = wv * 32 + cj * 16 + lo;
        float bias = bc[col];
#pragma unroll
        for (int r = 0; r < 4; ++r) {
            int row = mt * 16 + q4 * 4 + r;
            out[row * Ee + col] = acc[cj][r] + bias;
        }
    }
}

// ---------------------------------------------------------------------------
extern "C" void kernel_launch(void* const* d_in, const int* in_sizes, int n_in,
                              void* d_out, int out_size, void* d_ws, size_t ws_size,
                              hipStream_t stream)
{
    const float* q    = (const float*)d_in[0];
    const float* k    = (const float*)d_in[1];
    const float* v    = (const float*)d_in[2];
    const float* mask = (const float*)d_in[3];
    const float* Wq   = (const float*)d_in[4];
    const float* Wk   = (const float*)d_in[5];
    const float* Wv   = (const float*)d_in[6];
    const float* Wc   = (const float*)d_in[7];
    const float* bc   = (const float*)d_in[8];
    float* out = (float*)d_out;

    bf16* Qh = (bf16*)d_ws;                  // 16.78 MB each
    bf16* Kh = Qh + 8388608;
    bf16* Vt = Kh + 8388608;
    bf16* oc = Vt + 8388608;                 // total 67.1 MB of ws

    k_qkv<<<dim3(64, 8, 3), 256, 0, stream>>>(q, k, v, Wq, Wk, Wv, Qh, Kh, Vt);
    k_attn<<<dim3(64, 4), 512, 0, stream>>>(Qh, Kh, Vt, mask, oc);
    k_proj<<<dim3(512), 256, 0, stream>>>(oc, Wc, bc, out);
}

// Round 10
// 169.136 us; speedup vs baseline: 1.0153x; 1.0153x over previous
//
#include <hip/hip_runtime.h>

typedef __bf16 bf16;
typedef __attribute__((ext_vector_type(8))) __bf16 bf16x8;
typedef __attribute__((ext_vector_type(4))) __bf16 bf16x4;
typedef __attribute__((ext_vector_type(4))) float f32x4;

constexpr int Bb = 8;
constexpr int Ss = 1024;
constexpr int Ee = 128;
constexpr int Hh = 8;
constexpr int Dd = 128;
constexpr int HD = 1024;

// async 16B global -> LDS (wave-uniform LDS base + lane*16, per-lane global src)
__device__ __forceinline__ void gl_lds16(const bf16* gp, bf16* lp) {
    __builtin_amdgcn_global_load_lds(
        (const __attribute__((address_space(1))) unsigned int*)gp,
        (__attribute__((address_space(3))) unsigned int*)lp, 16, 0, 0);
}

// ---------------------------------------------------------------------------
// K1: QKV projection, fused fp32->bf16 staging (unchanged from R9).
// Q/K -> [b,h,s,d]; V -> [b,h,d,s] (operand swap).  Wq gets log2e/sqrt(128).
// ---------------------------------------------------------------------------
__global__ __launch_bounds__(256, 2) void k_qkv(
    const float* __restrict__ qin, const float* __restrict__ kin, const float* __restrict__ vin,
    const float* __restrict__ Wq, const float* __restrict__ Wk, const float* __restrict__ Wv,
    bf16* __restrict__ Qh, bf16* __restrict__ Kh, bf16* __restrict__ Vt)
{
    const int rb    = blockIdx.x;
    const int h     = blockIdx.y;
    const int which = blockIdx.z;
    const float* x = (which == 0) ? qin : (which == 1) ? kin : vin;
    const float* W = (which == 0) ? Wq  : (which == 1) ? Wk  : Wv;
    const float ws = (which == 0) ? 0.12751741530603157f : 1.0f;  // log2e/sqrt(128)

    __shared__ bf16 Xs[128][136];
    __shared__ bf16 Ws[128][136];

    const int tid  = threadIdx.x;
    const int wv   = tid >> 6;
    const int lane = tid & 63;
    const int lo   = lane & 15;
    const int q4   = lane >> 4;

#pragma unroll
    for (int t = 0; t < 8; ++t) {
        int c = tid + t * 256;
        int row = c >> 4, c8 = (c & 15) << 3;
        const float* xp = &x[(rb * 128 + row) * Ee + c8];
        float4 f0 = *(const float4*)xp;
        float4 f1 = *(const float4*)(xp + 4);
        bf16x8 p;
        p[0] = (bf16)f0.x; p[1] = (bf16)f0.y; p[2] = (bf16)f0.z; p[3] = (bf16)f0.w;
        p[4] = (bf16)f1.x; p[5] = (bf16)f1.y; p[6] = (bf16)f1.z; p[7] = (bf16)f1.w;
        *(bf16x8*)&Xs[row][c8] = p;
        const float* wp = &W[(h * 128 + row) * Ee + c8];
        float4 g0 = *(const float4*)wp;
        float4 g1 = *(const float4*)(wp + 4);
        bf16x8 w;
        w[0] = (bf16)(g0.x * ws); w[1] = (bf16)(g0.y * ws);
        w[2] = (bf16)(g0.z * ws); w[3] = (bf16)(g0.w * ws);
        w[4] = (bf16)(g1.x * ws); w[5] = (bf16)(g1.y * ws);
        w[6] = (bf16)(g1.z * ws); w[7] = (bf16)(g1.w * ws);
        *(bf16x8*)&Ws[row][c8] = w;
    }
    __syncthreads();

    const bf16 (*Ap)[136] = (which == 2) ? Ws : Xs;
    const bf16 (*Bp)[136] = (which == 2) ? Xs : Ws;

    f32x4 acc[2][8];
#pragma unroll
    for (int i = 0; i < 2; ++i)
#pragma unroll
        for (int j = 0; j < 8; ++j) acc[i][j] = f32x4{0.f, 0.f, 0.f, 0.f};

#pragma unroll
    for (int kq = 0; kq < 4; ++kq) {
        bf16x8 a[2], b8[8];
#pragma unroll
        for (int ri = 0; ri < 2; ++ri)
            a[ri] = *(const bf16x8*)&Ap[wv * 32 + ri * 16 + lo][kq * 32 + q4 * 8];
#pragma unroll
        for (int cj = 0; cj < 8; ++cj)
            b8[cj] = *(const bf16x8*)&Bp[cj * 16 + lo][kq * 32 + q4 * 8];
#pragma unroll
        for (int ri = 0; ri < 2; ++ri)
#pragma unroll
            for (int cj = 0; cj < 8; ++cj)
                acc[ri][cj] = __builtin_amdgcn_mfma_f32_16x16x32_bf16(
                    a[ri], b8[cj], acc[ri][cj], 0, 0, 0);
    }

    const int bb = rb >> 3;
    const int s0 = (rb & 7) * 128;
    if (which < 2) {
        bf16* dst = ((which == 0) ? Qh : Kh) + (bb * Hh + h) * Ss * Dd;
#pragma unroll
        for (int ri = 0; ri < 2; ++ri)
#pragma unroll
            for (int cj = 0; cj < 8; ++cj)
#pragma unroll
                for (int r = 0; r < 4; ++r) {
                    int row = wv * 32 + ri * 16 + q4 * 4 + r;
                    int col = cj * 16 + lo;
                    dst[(s0 + row) * Dd + col] = (bf16)acc[ri][cj][r];
                }
    } else {
        bf16* dst = Vt + (bb * Hh + h) * Dd * Ss;
#pragma unroll
        for (int ri = 0; ri < 2; ++ri)
#pragma unroll
            for (int cj = 0; cj < 8; ++cj)
#pragma unroll
                for (int r = 0; r < 4; ++r) {
                    int row = wv * 32 + ri * 16 + q4 * 4 + r;   // d
                    int col = cj * 16 + lo;                     // s-local
                    dst[row * Ss + s0 + col] = (bf16)acc[ri][cj][r];
                }
    }
}

// ---------------------------------------------------------------------------
// K2: streaming attention.  R8 structure, but the window's two 64-key tiles
// are computed in ONE fused dependency graph:
//   QK(A); QK(B); exp(A); PV(A); exp(B); PV(B)
// exp(A) is independent of QK(B) and exp(B) of PV(A), so the scheduler can
// interleave VALU with MFMA issue, and SIMD-paired waves co-issue across
// pipes (m114).  All layout/permutation math verbatim R8 (verified).
// block 512 = 8 waves (32 qrows); grid (64 bh, 4 qg); 1 block/CU.
// ---------------------------------------------------------------------------
__global__ __launch_bounds__(512, 2) void k_attn(
    const bf16* __restrict__ Qh, const bf16* __restrict__ Kh, const bf16* __restrict__ Vt,
    const float* __restrict__ mask, bf16* __restrict__ oc)
{
    const int bh = blockIdx.x;
    const int qg = blockIdx.y;     // 0..3, 256 qrows each
    const int b  = bh >> 3;
    const int h  = bh & 7;
    const int tid  = threadIdx.x;
    const int wv   = tid >> 6;     // 0..7
    const int lane = tid & 63;
    const int lo   = lane & 15;
    const int q4   = lane >> 4;

    __shared__ bf16 KsL[4][64 * 128];   // 4 x 16 KB  [key' perm][d-chunk swz]
    __shared__ bf16 VsL[4][128 * 64];   // 4 x 16 KB  [d][key-chunk swz]
    __shared__ float maskS[1024];       // 4 KB, pre-scaled by log2(e)

    const bf16* Qb = Qh + bh * Ss * Dd;
    const bf16* Kb = Kh + bh * Ss * Dd;
    const bf16* Vb = Vt + bh * Dd * Ss;

    auto stage = [&](int bi, int j0) {
#pragma unroll
        for (int t = 0; t < 2; ++t) {
            int i = wv * 2 + t;                    // 0..15
            int row = i * 4 + (lane >> 4);         // LDS row r' (key')
            int grow = (row & 32) + (((row >> 2) & 3) << 3)
                     + (((row >> 4) & 1) << 2) + (row & 3);
            int g = (lane & 15) ^ (row & 7);
            gl_lds16(Kb + (j0 + grow) * Dd + g * 8, &KsL[bi][i * 512]);
        }
#pragma unroll
        for (int t = 0; t < 2; ++t) {
            int i = wv * 2 + t;
            int row = i * 8 + (lane >> 3);         // d
            int g = (lane & 7) ^ (row & 7);
            gl_lds16(Vb + row * Ss + j0 + g * 8, &VsL[bi][i * 512]);
        }
    };

    stage(0, 0);
    stage(1, 64);   // window 0 in flight

#pragma unroll
    for (int t = 0; t < 2; ++t)
        maskS[tid + t * 512] = mask[b * Ss + tid + t * 512] * 1.4426950408889634f;

    // persistent Q fragments (pre-scaled): B-operand of QK.
    const int q0 = qg * 256 + wv * 32;
    bf16x8 qf[2][4];
#pragma unroll
    for (int nt = 0; nt < 2; ++nt)
#pragma unroll
        for (int kq = 0; kq < 4; ++kq)
            qf[nt][kq] = *(const bf16x8*)&Qb[(q0 + nt * 16 + lo) * Dd + kq * 32 + q4 * 8];

    f32x4 accO[8][2];                // O^T[d-tile dm][qrow-tile nt]
#pragma unroll
    for (int dm = 0; dm < 8; ++dm)
#pragma unroll
        for (int nt = 0; nt < 2; ++nt) accO[dm][nt] = f32x4{0.f, 0.f, 0.f, 0.f};
    float lsum[2] = {0.f, 0.f};

    const int sw = lo & 7;   // read-side chunk swizzle key

    // --- fused-window building blocks (layout math identical to R8) ---
    auto qk = [&](int bi, f32x4 (&sc)[4][2]) {
#pragma unroll
        for (int c = 0; c < 4; ++c)
#pragma unroll
            for (int nt = 0; nt < 2; ++nt) sc[c][nt] = f32x4{0.f, 0.f, 0.f, 0.f};
#pragma unroll
        for (int kq = 0; kq < 4; ++kq) {
            bf16x8 kf[4];
#pragma unroll
            for (int c = 0; c < 4; ++c)
                kf[c] = *(const bf16x8*)&KsL[bi][(c * 16 + lo) * 128 + (((kq << 2) + q4) ^ sw) * 8];
#pragma unroll
            for (int c = 0; c < 4; ++c)
#pragma unroll
                for (int nt = 0; nt < 2; ++nt)
                    sc[c][nt] = __builtin_amdgcn_mfma_f32_16x16x32_bf16(
                        kf[c], qf[nt][kq], sc[c][nt], 0, 0, 0);
        }
    };

    auto expP = [&](int j0, f32x4 (&sc)[4][2], bf16x8 (&p8)[2][2]) {
#pragma unroll
        for (int kb = 0; kb < 2; ++kb) {
#pragma unroll
            for (int t = 0; t < 2; ++t) {
                const float4 mv = *(const float4*)&maskS[j0 + kb * 32 + q4 * 8 + t * 4];
                const int c = kb * 2 + t;
#pragma unroll
                for (int nt = 0; nt < 2; ++nt) {
                    float e0 = __builtin_amdgcn_exp2f(sc[c][nt][0] + mv.x);
                    float e1 = __builtin_amdgcn_exp2f(sc[c][nt][1] + mv.y);
                    float e2 = __builtin_amdgcn_exp2f(sc[c][nt][2] + mv.z);
                    float e3 = __builtin_amdgcn_exp2f(sc[c][nt][3] + mv.w);
                    lsum[nt] += (e0 + e1) + (e2 + e3);
                    p8[kb][nt][t * 4 + 0] = (bf16)e0;
                    p8[kb][nt][t * 4 + 1] = (bf16)e1;
                    p8[kb][nt][t * 4 + 2] = (bf16)e2;
                    p8[kb][nt][t * 4 + 3] = (bf16)e3;
                }
            }
        }
    };

    auto pv = [&](int bi, bf16x8 (&p8)[2][2]) {
#pragma unroll
        for (int kb = 0; kb < 2; ++kb)
#pragma unroll
            for (int dm = 0; dm < 8; ++dm) {
                bf16x8 vf = *(const bf16x8*)&VsL[bi][(dm * 16 + lo) * 64 + (((kb << 2) + q4) ^ sw) * 8];
#pragma unroll
                for (int nt = 0; nt < 2; ++nt)
                    accO[dm][nt] = __builtin_amdgcn_mfma_f32_16x16x32_bf16(
                        vf, p8[kb][nt], accO[dm][nt], 0, 0, 0);
            }
    };

    const bool grpB = (wv >= 4);   // SIMD-paired waves use opposite A/B roles

    for (int w = 0; w < 8; ++w) {
        const int t0 = 2 * w;
        __syncthreads();                       // window w's 2 buffers ready
        if (w < 7) {                           // prefetch window w+1
            stage((t0 + 2) & 3, (t0 + 2) * 64);
            stage((t0 + 3) & 3, (t0 + 3) * 64);
        }
        int biA = t0 & 3,       jA = t0 * 64;
        int biB = (t0 + 1) & 3, jB = (t0 + 1) * 64;
        if (grpB) { int tb = biA; biA = biB; biB = tb; int tj = jA; jA = jB; jB = tj; }

        f32x4 scA[4][2], scB[4][2];
        bf16x8 p8A[2][2], p8B[2][2];
        qk(biA, scA);          // MFMA chain A
        qk(biB, scB);          // MFMA chain B (independent of exp A)
        expP(jA, scA, p8A);    // VALU — interleavable with QK(B)
        pv(biA, p8A);          // MFMA chain A
        expP(jB, scB, p8B);    // VALU — interleavable with PV(A)
        pv(biB, p8B);          // MFMA chain B
    }

    // epilogue: row sums (reduce over q4 quads), normalize, store O.
#pragma unroll
    for (int nt = 0; nt < 2; ++nt) {
        float s = lsum[nt];
        s += __shfl_xor(s, 16, 64);
        s += __shfl_xor(s, 32, 64);
        float inv = 1.0f / (s + 1e-12f);
        int sg = q0 + nt * 16 + lo;
        bf16* dst = oc + (b * Ss + sg) * HD + h * 128;
#pragma unroll
        for (int dm = 0; dm < 8; ++dm) {
            bf16x4 o;
#pragma unroll
            for (int r = 0; r < 4; ++r) o[r] = (bf16)(accO[dm][nt][r] * inv);
            *(bf16x4*)&dst[dm * 16 + q4 * 4] = o;
        }
    }
}

// ---------------------------------------------------------------------------
// K3: output projection + bias, streaming (unchanged).
// ---------------------------------------------------------------------------
__global__ __launch_bounds__(256, 4) void k_proj(
    const bf16* __restrict__ oc, const float* __restrict__ Wc,
    const float* __restrict__ bc, float* __restrict__ out)
{
    const int mt   = blockIdx.x;
    const int tid  = threadIdx.x;
    const int wv   = tid >> 6;
    const int lane = tid & 63;
    const int lo   = lane & 15;
    const int q4   = lane >> 4;

    f32x4 acc[2];
    acc[0] = f32x4{0.f, 0.f, 0.f, 0.f};
    acc[1] = f32x4{0.f, 0.f, 0.f, 0.f};

    const bf16* arow = oc + (mt * 16 + lo) * HD + q4 * 8;

    for (int kc = 0; kc < 8; ++kc) {
        const int k0 = kc * 128;
        bf16x8 a[4];
#pragma unroll
        for (int kq = 0; kq < 4; ++kq)
            a[kq] = *(const bf16x8*)&arow[k0 + kq * 32];
#pragma unroll
        for (int cj = 0; cj < 2; ++cj) {
            const int n = wv * 32 + cj * 16 + lo;
#pragma unroll
            for (int kq = 0; kq < 4; ++kq) {
                const float* wp = &Wc[n * HD + k0 + kq * 32 + q4 * 8];
                float4 f0 = *(const float4*)wp;
                float4 f1 = *(const float4*)(wp + 4);
                bf16x8 bfr;
                bfr[0] = (bf16)f0.x; bfr[1] = (bf16)f0.y; bfr[2] = (bf16)f0.z; bfr[3] = (bf16)f0.w;
                bfr[4] = (bf16)f1.x; bfr[5] = (bf16)f1.y; bfr[6] = (bf16)f1.z; bfr[7] = (bf16)f1.w;
                acc[cj] = __builtin_amdgcn_mfma_f32_16x16x32_bf16(
                    a[kq], bfr, acc[cj], 0, 0, 0);
            }
        }
    }

#pragma unroll
    for (int cj = 0; cj < 2; ++cj) {
        int col = wv * 32 + cj * 16 + lo;
        float bias = bc[col];
#pragma unroll
        for (int r = 0; r < 4; ++r) {
            int row = mt * 16 + q4 * 4 + r;
            out[row * Ee + col] = acc[cj][r] + bias;
        }
    }
}

// ---------------------------------------------------------------------------
extern "C" void kernel_launch(void* const* d_in, const int* in_sizes, int n_in,
                              void* d_out, int out_size, void* d_ws, size_t ws_size,
                              hipStream_t stream)
{
    const float* q    = (const float*)d_in[0];
    const float* k    = (const float*)d_in[1];
    const float* v    = (const float*)d_in[2];
    const float* mask = (const float*)d_in[3];
    const float* Wq   = (const float*)d_in[4];
    const float* Wk   = (const float*)d_in[5];
    const float* Wv   = (const float*)d_in[6];
    const float* Wc   = (const float*)d_in[7];
    const float* bc   = (const float*)d_in[8];
    float* out = (float*)d_out;

    bf16* Qh = (bf16*)d_ws;                  // 16.78 MB each
    bf16* Kh = Qh + 8388608;
    bf16* Vt = Kh + 8388608;
    bf16* oc = Vt + 8388608;                 // total 67.1 MB of ws

    k_qkv<<<dim3(64, 8, 3), 256, 0, stream>>>(q, k, v, Wq, Wk, Wv, Qh, Kh, Vt);
    k_attn<<<dim3(64, 4), 512, 0, stream>>>(Qh, Kh, Vt, mask, oc);
    k_proj<<<dim3(512), 256, 0, stream>>>(oc, Wc, bc, out);
}